// Round 13
// baseline (384.534 us; speedup 1.0000x reference)
//
#include <hip/hip_runtime.h>

#define LOG2E 1.442695040888963f

typedef float f32x2 __attribute__((ext_vector_type(2)));

// packed fp32 FMA / MUL (VOP3P; same FLOP rate as scalar fp32 but half the
// instruction slots)
static __device__ __forceinline__ void pkfma(f32x2& acc, f32x2 a, f32x2 b) {
    asm("v_pk_fma_f32 %0, %1, %2, %0" : "+v"(acc) : "v"(a), "v"(b));
}
static __device__ __forceinline__ void pkmul(f32x2& d, f32x2 a, f32x2 b) {
    asm("v_pk_mul_f32 %0, %1, %2" : "=v"(d) : "v"(a), "v"(b));
}

// One batch element per 64-lane wave (2048 blocks, 2 waves/SIMD).
// Gate rows 0..103 = i,f,g,o. Lane mapping (j = l & 31, rows clamped j>=26):
//   lanes  0..25: dot0 = i_j (sigmoid), dot1 = g_j (scaled tanh)
//   lanes 32..57: dot0 = f_j (sigmoid), dot1 = o_j (sigmoid)
// Cross-lane i*g -> c-lane: permlane32_swap(y0, pr), rcv = sw[0]
// (proven R12: sw[0][32+j] = vsrc_old[j]; y0 live-after => distinct regs).
// Cell state C' = -2*log2e*c; h = fma(rcp(1+exp2(C')), 2*sig(o), -sig(o)).
//
// h TRANSPORT (new): 26 ds_bpermute_b32 straight from the hv REGISTER of
// lanes 32..57 -- no ds_write, no LDS memory, no write->read round-trip on
// the serial chain (R12's exposed ~115cy/step stall). Uniform addresses
// (32+q)<<2 live in 26 loop-invariant VGPRs; the builtin lets the compiler
// track lgkmcnt (no inline-asm waitcnt hazards). After the loop every lane
// holds h in registers -> LDS-free epilogue; hbuf deleted.
__launch_bounds__(64, 2)
__global__ void lstm_char_kernel(const int* __restrict__ x,      // [B,T] int32
                                 const float* __restrict__ E,     // [26,26]
                                 const float* __restrict__ W_ih,  // [104,26]
                                 const float* __restrict__ W_hh,  // [104,26]
                                 const float* __restrict__ b_ih,  // [104]
                                 const float* __restrict__ b_hh,  // [104]
                                 const float* __restrict__ W_lin, // [26,26]
                                 const float* __restrict__ b_lin, // [26]
                                 float* __restrict__ out,         // [B,26]
                                 int T)
{
    constexpr int H = 26;

    __shared__ __align__(16) f32x2 P[26][64];           // 13312 B
    __shared__ __align__(8) unsigned short chars[1032]; // 2064 B

    const int b = blockIdx.x;
    const int l = threadIdx.x;
    const int j = l & 31;
    const bool lo = (l < 32);
    const int rr = (j < 26) ? j : 0;            // clamp inactive lanes to row 0
    const int r0 = lo ? rr : 26 + rr;           // i or f row
    const int r1 = lo ? 52 + rr : 78 + rr;      // g or o row

    // ---- stage char sequence as u16 P-row byte offsets (64 pairs * 8 = 512) ----
    for (int t = l; t < T; t += 64)
        chars[t] = (unsigned short)(x[(size_t)b * T + t] * 512);
    if (l < 8) chars[1024 + l] = 0;

    // exp2 prescales: dot0 (i or f) sigmoid; dot1 scaled-tanh (g) or sigmoid (o)
    const float m0 = -LOG2E;
    const float m1 = lo ? (-2.0f * LOG2E) : (-LOG2E);
    const float s1 = lo ? (-4.0f * LOG2E) : 1.0f;   // y1 = fma(rcp, s1, d1)
    const float d1 = lo ? ( 2.0f * LOG2E) : 0.0f;

    // ---- prescaled fp32 recurrent weights as packed pairs ----
    f32x2 wh0p[13], wh1p[13];
    #pragma unroll
    for (int k = 0; k < 13; ++k) {
        wh0p[k] = f32x2{W_hh[r0 * H + 2 * k] * m0, W_hh[r0 * H + 2 * k + 1] * m0};
        wh1p[k] = f32x2{W_hh[r1 * H + 2 * k] * m1, W_hh[r1 * H + 2 * k + 1] * m1};
    }

    // ---- build prescaled pair-interleaved P table (E direct from global) ----
    {
        float wi0[H], wi1[H];
        #pragma unroll
        for (int k = 0; k < H; ++k) {
            wi0[k] = W_ih[r0 * H + k];
            wi1[k] = W_ih[r1 * H + k];
        }
        const float bias0 = b_ih[r0] + b_hh[r0];
        const float bias1 = b_ih[r1] + b_hh[r1];
        for (int ch = 0; ch < 26; ++ch) {
            float a0 = bias0, a1 = bias1;
            #pragma unroll
            for (int k = 0; k < H; ++k) {
                float e = E[ch * H + k];
                a0 = fmaf(wi0[k], e, a0);
                a1 = fmaf(wi1[k], e, a1);
            }
            P[ch][l] = f32x2{a0 * m0, a1 * m1};
        }
    }
    __syncthreads();

    // ---- anti-phase skew: 0..7 units of 4 dependent v_rcp (~50cy each) ----
    {
        unsigned hsh = (blockIdx.x * 2654435761u) >> 29;
        float dch = (float)(l + 1);
        for (unsigned i = 0; i < hsh; ++i) {
            asm volatile("v_rcp_f32 %0, %0\n\t"
                         "v_rcp_f32 %0, %0\n\t"
                         "v_rcp_f32 %0, %0\n\t"
                         "v_rcp_f32 %0, %0" : "+v"(dch));
        }
        asm volatile("" :: "v"(dch));
    }

    const char* Pb = (const char*)&P[0][0];
    const int lane8 = l << 3;

    // bpermute byte addresses for lanes 32..57 (uniform, loop-invariant VGPRs)
    int bpad[26];
    #pragma unroll
    for (int q = 0; q < 26; ++q) bpad[q] = (32 + q) << 2;

    // ---- pipeline prologue: h(0) = 0 broadcast ----
    f32x2 hp[13];
    #pragma unroll
    for (int q = 0; q < 13; ++q) hp[q] = f32x2{0.0f, 0.0f};

    int poffn = chars[1];
    f32x2 pa = *(const f32x2*)(Pb + (int)chars[0] + lane8);
    float C = 0.0f;                   // C' = -2*log2e*c, lives in lanes 32..57

    #pragma unroll 2
    for (int t = 0; t < T; ++t) {
        // prefetch P pair for t+1, char offset for t+2 (off critical path)
        f32x2 pn = *(const f32x2*)(Pb + poffn + lane8);
        int poff2 = chars[t + 2];

        // two dot products on the register-broadcast h (no LDS read!)
        f32x2 A0, A1, B0, B1;
        pkmul(A0, hp[0], wh0p[0]);
        pkmul(A1, hp[1], wh0p[1]);
        pkmul(B0, hp[0], wh1p[0]);
        pkmul(B1, hp[1], wh1p[1]);
        #pragma unroll
        for (int k = 2; k < 12; k += 2) {
            pkfma(A0, hp[k],     wh0p[k]);
            pkfma(A1, hp[k + 1], wh0p[k + 1]);
            pkfma(B0, hp[k],     wh1p[k]);
            pkfma(B1, hp[k + 1], wh1p[k + 1]);
        }
        pkfma(A0, hp[12], wh0p[12]);
        pkfma(B0, hp[12], wh1p[12]);
        f32x2 sa = A0 + A1;
        f32x2 sb = B0 + B1;
        const float a0s = sa.x + sa.y + pa.x;   // prescaled for exp2
        const float a1s = sb.x + sb.y + pa.y;

        // activations
        float y0 = __builtin_amdgcn_rcpf(1.0f + __builtin_amdgcn_exp2f(a0s));
        float y1 = fmaf(__builtin_amdgcn_rcpf(1.0f + __builtin_amdgcn_exp2f(a1s)),
                        s1, d1);
        float y1_2 = y1 + y1;

        // cross-lane: lanes 32..57 receive scaled i*g from lanes 0..25
        float pr = y0 * y1;
        auto sw = __builtin_amdgcn_permlane32_swap(__float_as_int(y0),
                                                   __float_as_int(pr),
                                                   false, false);
        float rcv = __int_as_float(sw[0]);

        // C', h update (meaningful in lanes 32..57)
        C = fmaf(y0, C, rcv);
        float rc = __builtin_amdgcn_rcpf(1.0f + __builtin_amdgcn_exp2f(C));
        float hv = fmaf(rc, y1_2, -y1);          // sig(o)*tanh(c)

        // broadcast h for t+1: 26 ds_bpermute straight from the hv register
        const int hb = __float_as_int(hv);
        #pragma unroll
        for (int q = 0; q < 13; ++q) {
            hp[q].x = __int_as_float(__builtin_amdgcn_ds_bpermute(bpad[2 * q],     hb));
            hp[q].y = __int_as_float(__builtin_amdgcn_ds_bpermute(bpad[2 * q + 1], hb));
        }

        pa = pn; poffn = poff2;
    }

    // ---- final linear: every lane holds all h in registers ----
    if (l < H) {
        float acc = b_lin[l];
        #pragma unroll
        for (int q = 0; q < 13; ++q) {
            acc = fmaf(W_lin[l * H + 2 * q],     hp[q].x, acc);
            acc = fmaf(W_lin[l * H + 2 * q + 1], hp[q].y, acc);
        }
        out[(size_t)b * H + l] = acc;
    }
}

extern "C" void kernel_launch(void* const* d_in, const int* in_sizes, int n_in,
                              void* d_out, int out_size, void* d_ws, size_t ws_size,
                              hipStream_t stream) {
    const int*   x     = (const int*)d_in[0];
    const float* E     = (const float*)d_in[1];
    const float* W_ih  = (const float*)d_in[2];
    const float* W_hh  = (const float*)d_in[3];
    const float* b_ih  = (const float*)d_in[4];
    const float* b_hh  = (const float*)d_in[5];
    const float* W_lin = (const float*)d_in[6];
    const float* b_lin = (const float*)d_in[7];
    float* out = (float*)d_out;

    const int T = 1024;
    const int B = in_sizes[0] / T;   // 2048

    lstm_char_kernel<<<B, 64, 0, stream>>>(x, E, W_ih, W_hh, b_ih, b_hh,
                                           W_lin, b_lin, out, T);
}

// Round 14
// 342.934 us; speedup vs baseline: 1.1213x; 1.1213x over previous
//
#include <hip/hip_runtime.h>

#define LOG2E 1.442695040888963f

typedef float f32x2 __attribute__((ext_vector_type(2)));

// One batch element per 64-lane wave (2048 blocks, 2 waves/SIMD).
// Gate rows 0..103 = i,f,g,o. Lane mapping (j = l & 31, rows clamped j>=26):
//   lanes  0..25: dot0 = i_j (sigmoid), dot1 = g_j (scaled tanh)
//   lanes 32..57: dot0 = f_j (sigmoid), dot1 = o_j (sigmoid)
// Cross-lane i*g -> c-lane: permlane32_swap(y0, pr), rcv = sw[0]
// (semantics HW-proven in R12: sw[0][32+j] = vsrc_old[j]; passed 9.8e-4).
// Cell state C' = -2*log2e*c; h = fma(rcp(1+exp2(C')), 2*sig(o), -sig(o)).
//
// h TRANSPORT (the R14 change): 26 v_readlane -> wave-uniform SGPRs, consumed
// by SCALAR v_fma_f32 (SGPR src legal, 1 scalar read). This removes the
// ~250cy LDS write->read round trip that R11-R13 showed is the critical-path
// floor (wall 766cy/step = chain, issue only 536). Unlike R6 (which packed
// SGPR pairs via SALU + "s"(long) asm and became issue-bound), there is NO
// packing and NO inline asm: readlane feeds fma directly. hbuf deleted;
// the epilogue reads h straight from SGPRs.
__launch_bounds__(64, 2)
__global__ void lstm_char_kernel(const int* __restrict__ x,      // [B,T] int32
                                 const float* __restrict__ E,     // [26,26]
                                 const float* __restrict__ W_ih,  // [104,26]
                                 const float* __restrict__ W_hh,  // [104,26]
                                 const float* __restrict__ b_ih,  // [104]
                                 const float* __restrict__ b_hh,  // [104]
                                 const float* __restrict__ W_lin, // [26,26]
                                 const float* __restrict__ b_lin, // [26]
                                 float* __restrict__ out,         // [B,26]
                                 int T)
{
    constexpr int H = 26;

    __shared__ __align__(16) f32x2 P[26][64];           // 13312 B, pair-interleaved
    __shared__ __align__(8) unsigned short chars[1032]; // 2064 B, premultiplied offs

    const int b = blockIdx.x;
    const int l = threadIdx.x;
    const int j = l & 31;
    const bool lo = (l < 32);
    const int rr = (j < 26) ? j : 0;            // clamp inactive lanes to row 0
    const int r0 = lo ? rr : 26 + rr;           // i or f row
    const int r1 = lo ? 52 + rr : 78 + rr;      // g or o row

    // ---- stage char sequence as u16 P-row byte offsets (64 pairs * 8 = 512) ----
    for (int t = l; t < T; t += 64)
        chars[t] = (unsigned short)(x[(size_t)b * T + t] * 512);
    if (l < 8) chars[1024 + l] = 0;

    // exp2 prescales: dot0 (i or f) sigmoid; dot1 scaled-tanh (g) or sigmoid (o)
    const float m0 = -LOG2E;
    const float m1 = lo ? (-2.0f * LOG2E) : (-LOG2E);
    const float s1 = lo ? (-4.0f * LOG2E) : 1.0f;   // y1 = fma(rcp, s1, d1)
    const float d1 = lo ? ( 2.0f * LOG2E) : 0.0f;

    // ---- prescaled fp32 recurrent weights (scalar per k; 52 VGPRs) ----
    float wh0[H], wh1[H];
    #pragma unroll
    for (int k = 0; k < H; ++k) {
        wh0[k] = W_hh[r0 * H + k] * m0;
        wh1[k] = W_hh[r1 * H + k] * m1;
    }

    // ---- build prescaled pair-interleaved P table (E direct from global) ----
    {
        float wi0[H], wi1[H];
        #pragma unroll
        for (int k = 0; k < H; ++k) {
            wi0[k] = W_ih[r0 * H + k];
            wi1[k] = W_ih[r1 * H + k];
        }
        const float bias0 = b_ih[r0] + b_hh[r0];
        const float bias1 = b_ih[r1] + b_hh[r1];
        for (int ch = 0; ch < 26; ++ch) {
            float a0 = bias0, a1 = bias1;
            #pragma unroll
            for (int k = 0; k < H; ++k) {
                float e = E[ch * H + k];
                a0 = fmaf(wi0[k], e, a0);
                a1 = fmaf(wi1[k], e, a1);
            }
            P[ch][l] = f32x2{a0 * m0, a1 * m1};
        }
    }
    __syncthreads();

    const char* Pb = (const char*)&P[0][0];
    const int lane8 = l << 3;

    // ---- pipeline prologue: h(0) = 0 (wave-uniform scalars) ----
    float hs[H];
    #pragma unroll
    for (int k = 0; k < H; ++k) hs[k] = 0.0f;

    int poffn = chars[1];
    f32x2 pa = *(const f32x2*)(Pb + (int)chars[0] + lane8);
    float C = 0.0f;                   // C' = -2*log2e*c, lives in lanes 32..57

    #pragma unroll 2
    for (int t = 0; t < T; ++t) {
        // prefetch P pair for t+1, char offset for t+2 (off critical path)
        f32x2 pn = *(const f32x2*)(Pb + poffn + lane8);
        int poff2 = chars[t + 2];

        // two dot products; h from wave-uniform SGPRs (no LDS on the chain).
        // 2 chains per dot, P-term folded into the chain start.
        float u0 = pa.x, u1 = 0.0f, u2 = pa.y, u3 = 0.0f;
        #pragma unroll
        for (int k = 0; k < H; k += 2) {
            u0 = fmaf(wh0[k],     hs[k],     u0);
            u1 = fmaf(wh0[k + 1], hs[k + 1], u1);
            u2 = fmaf(wh1[k],     hs[k],     u2);
            u3 = fmaf(wh1[k + 1], hs[k + 1], u3);
        }
        const float a0s = u0 + u1;       // prescaled for exp2
        const float a1s = u2 + u3;

        // activations
        float y0 = __builtin_amdgcn_rcpf(1.0f + __builtin_amdgcn_exp2f(a0s));
        float y1 = fmaf(__builtin_amdgcn_rcpf(1.0f + __builtin_amdgcn_exp2f(a1s)),
                        s1, d1);
        float y1_2 = y1 + y1;

        // cross-lane: lanes 32..57 receive scaled i*g from lanes 0..25
        float pr = y0 * y1;
        auto sw = __builtin_amdgcn_permlane32_swap(__float_as_int(y0),
                                                   __float_as_int(pr),
                                                   false, false);
        float rcv = __int_as_float(sw[0]);

        // C', h update (meaningful in lanes 32..57)
        C = fmaf(y0, C, rcv);
        float rc = __builtin_amdgcn_rcpf(1.0f + __builtin_amdgcn_exp2f(C));
        float hv = fmaf(rc, y1_2, -y1);          // sig(o)*tanh(c)

        // broadcast h for t+1: 26 readlanes -> SGPRs (no packing, no LDS)
        const int hb = __float_as_int(hv);
        #pragma unroll
        for (int k = 0; k < H; ++k)
            hs[k] = __int_as_float(__builtin_amdgcn_readlane(hb, 32 + k));

        pa = pn; poffn = poff2;
    }

    // ---- final linear: h already wave-uniform in SGPRs ----
    if (l < H) {
        float acc = b_lin[l];
        #pragma unroll
        for (int k = 0; k < H; ++k)
            acc = fmaf(W_lin[l * H + k], hs[k], acc);
        out[(size_t)b * H + l] = acc;
    }
}

extern "C" void kernel_launch(void* const* d_in, const int* in_sizes, int n_in,
                              void* d_out, int out_size, void* d_ws, size_t ws_size,
                              hipStream_t stream) {
    const int*   x     = (const int*)d_in[0];
    const float* E     = (const float*)d_in[1];
    const float* W_ih  = (const float*)d_in[2];
    const float* W_hh  = (const float*)d_in[3];
    const float* b_ih  = (const float*)d_in[4];
    const float* b_hh  = (const float*)d_in[5];
    const float* W_lin = (const float*)d_in[6];
    const float* b_lin = (const float*)d_in[7];
    float* out = (float*)d_out;

    const int T = 1024;
    const int B = in_sizes[0] / T;   // 2048

    lstm_char_kernel<<<B, 64, 0, stream>>>(x, E, W_ih, W_hh, b_ih, b_hh,
                                           W_lin, b_lin, out, T);
}

// Round 15
// 275.083 us; speedup vs baseline: 1.3979x; 1.2467x over previous
//
#include <hip/hip_runtime.h>

#define LOG2E 1.442695040888963f

typedef float f32x2 __attribute__((ext_vector_type(2)));

// packed fp32 FMA / MUL (VOP3P; halves dot instruction count)
static __device__ __forceinline__ void pkfma(f32x2& acc, f32x2 a, f32x2 b) {
    asm("v_pk_fma_f32 %0, %1, %2, %0" : "+v"(acc) : "v"(a), "v"(b));
}
static __device__ __forceinline__ void pkmul(f32x2& d, f32x2 a, f32x2 b) {
    asm("v_pk_mul_f32 %0, %1, %2" : "=v"(d) : "v"(a), "v"(b));
}

// One batch element per 64-lane wave (2048 blocks, 2 waves/SIMD).
// Lane mapping (j = l & 31, rows clamped j>=26):
//   lanes  0..25: dot0 = i_j (sigmoid), dot1 = g_j (scaled tanh)
//   lanes 32..57: dot0 = f_j (sigmoid), dot1 = o_j (sigmoid)
// Cross-lane i*g -> c-lane: permlane32_swap(y0, pr), rcv = sw[0] (HW-proven R12).
// Cell state C' = -2*log2e*c; h = fma(rcp(1+exp2(C')), 2*sig(o), -sig(o)).
//
// R15 changes vs R12 (transport scoreboard: LDS 766cy wall < readlane 914 <
// bpermute 1000 -- LDS transport kept):
//  1. hbuf DOUBLE-BUFFERED with compile-time buffer selection (manual x2
//     unroll): same-iteration h-reads and h-write hit DIFFERENT buffers, so
//     the compiler cannot emit a WAR lgkmcnt fence before the write. The
//     true write->read dep rides the in-order DS pipe (~150-240cy) instead
//     of a fenced ~360cy (the unexplained gap in the 766cy wall).
//  2. chars LDS staging deleted: x[b*T + (t+2)&1023] read directly each step
//     (wave-uniform -> s_load, prefetched 2 steps = ~1500cy slack). One
//     fewer DS op per step in the lgkm stream; -2KB LDS.
__launch_bounds__(64, 2)
__global__ void lstm_char_kernel(const int* __restrict__ x,      // [B,T] int32
                                 const float* __restrict__ E,     // [26,26]
                                 const float* __restrict__ W_ih,  // [104,26]
                                 const float* __restrict__ W_hh,  // [104,26]
                                 const float* __restrict__ b_ih,  // [104]
                                 const float* __restrict__ b_hh,  // [104]
                                 const float* __restrict__ W_lin, // [26,26]
                                 const float* __restrict__ b_lin, // [26]
                                 float* __restrict__ out,         // [B,26]
                                 int T)
{
    constexpr int H = 26;

    __shared__ __align__(16) f32x2 P[26][64];   // 13312 B, pair-interleaved
    __shared__ __align__(16) float hb[2][32];   // double-buffered h

    const int b = blockIdx.x;
    const int l = threadIdx.x;
    const int j = l & 31;
    const bool lo = (l < 32);
    const int rr = (j < 26) ? j : 0;            // clamp inactive lanes to row 0
    const int r0 = lo ? rr : 26 + rr;           // i or f row
    const int r1 = lo ? 52 + rr : 78 + rr;      // g or o row
    const size_t xbase = (size_t)b * T;

    hb[0][j] = 0.0f;                            // only buf0 read at t=0
    hb[1][j] = 0.0f;

    // exp2 prescales: dot0 (i or f) sigmoid; dot1 scaled-tanh (g) or sigmoid (o)
    const float m0 = -LOG2E;
    const float m1 = lo ? (-2.0f * LOG2E) : (-LOG2E);
    const float s1 = lo ? (-4.0f * LOG2E) : 1.0f;   // y1 = fma(rcp, s1, d1)
    const float d1 = lo ? ( 2.0f * LOG2E) : 0.0f;

    // ---- prescaled fp32 recurrent weights as packed pairs ----
    f32x2 wh0p[13], wh1p[13];
    #pragma unroll
    for (int k = 0; k < 13; ++k) {
        wh0p[k] = f32x2{W_hh[r0 * H + 2 * k] * m0, W_hh[r0 * H + 2 * k + 1] * m0};
        wh1p[k] = f32x2{W_hh[r1 * H + 2 * k] * m1, W_hh[r1 * H + 2 * k + 1] * m1};
    }

    // ---- build prescaled pair-interleaved P table (E direct from global) ----
    {
        float wi0[H], wi1[H];
        #pragma unroll
        for (int k = 0; k < H; ++k) {
            wi0[k] = W_ih[r0 * H + k];
            wi1[k] = W_ih[r1 * H + k];
        }
        const float bias0 = b_ih[r0] + b_hh[r0];
        const float bias1 = b_ih[r1] + b_hh[r1];
        for (int ch = 0; ch < 26; ++ch) {
            float a0 = bias0, a1 = bias1;
            #pragma unroll
            for (int k = 0; k < H; ++k) {
                float e = E[ch * H + k];
                a0 = fmaf(wi0[k], e, a0);
                a1 = fmaf(wi1[k], e, a1);
            }
            P[ch][l] = f32x2{a0 * m0, a1 * m1};
        }
    }
    __syncthreads();

    // ---- anti-phase skew: 0..7 units of 4 dependent v_rcp ----
    {
        unsigned hsh = (blockIdx.x * 2654435761u) >> 29;
        float dch = (float)(l + 1);
        for (unsigned i = 0; i < hsh; ++i) {
            asm volatile("v_rcp_f32 %0, %0\n\t"
                         "v_rcp_f32 %0, %0\n\t"
                         "v_rcp_f32 %0, %0\n\t"
                         "v_rcp_f32 %0, %0" : "+v"(dch));
        }
        asm volatile("" :: "v"(dch));
    }

    const char* Pb = (const char*)&P[0][0];
    const int lane8 = l << 3;
    const int tm = T - 1;                       // T = 1024 (pow2 mask)
    // write slot: lanes 32..57 -> 0..25 (real h); all junk lanes clamped into
    // slots 26..31 of the SAME 32-float buffer (collisions only among junk,
    // never read: readers consume floats 0..25 = 13 b64 pairs exactly).
    int hidx = (l - 32) & 63;
    hidx = hidx < 32 ? hidx : 31;

    // ---- pipeline prologue ----
    int poffn = (int)x[xbase + 1] * 512;
    f32x2 pa;
    {
        int p0 = (int)x[xbase] * 512;
        pa = *(const f32x2*)(Pb + p0 + lane8);
    }
    float C = 0.0f;                   // C' = -2*log2e*c, lives in lanes 32..57

#define LSTM_STEP(RB, WB, tc)                                                 \
    {                                                                         \
        f32x2 hp[13];                                                         \
        _Pragma("unroll")                                                     \
        for (int q = 0; q < 13; ++q) hp[q] = ((const f32x2*)(RB))[q];         \
        f32x2 pn = *(const f32x2*)(Pb + poffn + lane8);                       \
        int poff2 = (int)x[xbase + (((tc) + 2) & tm)] * 512;                  \
        f32x2 A0, A1, B0, B1;                                                 \
        pkmul(A0, hp[0], wh0p[0]);                                            \
        pkmul(A1, hp[1], wh0p[1]);                                            \
        pkmul(B0, hp[0], wh1p[0]);                                            \
        pkmul(B1, hp[1], wh1p[1]);                                            \
        _Pragma("unroll")                                                     \
        for (int k = 2; k < 12; k += 2) {                                     \
            pkfma(A0, hp[k],     wh0p[k]);                                    \
            pkfma(A1, hp[k + 1], wh0p[k + 1]);                                \
            pkfma(B0, hp[k],     wh1p[k]);                                    \
            pkfma(B1, hp[k + 1], wh1p[k + 1]);                                \
        }                                                                     \
        pkfma(A0, hp[12], wh0p[12]);                                          \
        pkfma(B0, hp[12], wh1p[12]);                                          \
        f32x2 sa = A0 + A1;                                                   \
        f32x2 sb = B0 + B1;                                                   \
        const float a0s = sa.x + sa.y + pa.x;                                 \
        const float a1s = sb.x + sb.y + pa.y;                                 \
        float y0 = __builtin_amdgcn_rcpf(1.0f + __builtin_amdgcn_exp2f(a0s)); \
        float y1 = fmaf(__builtin_amdgcn_rcpf(                                \
                            1.0f + __builtin_amdgcn_exp2f(a1s)), s1, d1);     \
        float y1_2 = y1 + y1;                                                 \
        float pr = y0 * y1;                                                   \
        auto sw = __builtin_amdgcn_permlane32_swap(__float_as_int(y0),        \
                                                   __float_as_int(pr),        \
                                                   false, false);             \
        float rcv = __int_as_float(sw[0]);                                    \
        C = fmaf(y0, C, rcv);                                                 \
        float rc = __builtin_amdgcn_rcpf(1.0f + __builtin_amdgcn_exp2f(C));   \
        float hv = fmaf(rc, y1_2, -y1);                                       \
        (WB)[hidx] = hv;                                                      \
        pa = pn; poffn = poff2;                                               \
    }

    for (int t = 0; t < T; t += 2) {
        LSTM_STEP(hb[0], hb[1], t);       // read buf0, write buf1
        LSTM_STEP(hb[1], hb[0], t + 1);   // read buf1, write buf0
    }
#undef LSTM_STEP

    __syncthreads();

    // ---- final linear (T even => last write went to hb[0]) ----
    if (l < H) {
        float acc = b_lin[l];
        #pragma unroll
        for (int k = 0; k < H; ++k)
            acc = fmaf(W_lin[l * H + k], hb[0][k], acc);
        out[(size_t)b * H + l] = acc;
    }
}

extern "C" void kernel_launch(void* const* d_in, const int* in_sizes, int n_in,
                              void* d_out, int out_size, void* d_ws, size_t ws_size,
                              hipStream_t stream) {
    const int*   x     = (const int*)d_in[0];
    const float* E     = (const float*)d_in[1];
    const float* W_ih  = (const float*)d_in[2];
    const float* W_hh  = (const float*)d_in[3];
    const float* b_ih  = (const float*)d_in[4];
    const float* b_hh  = (const float*)d_in[5];
    const float* W_lin = (const float*)d_in[6];
    const float* b_lin = (const float*)d_in[7];
    float* out = (float*)d_out;

    const int T = 1024;
    const int B = in_sizes[0] / T;   // 2048

    lstm_char_kernel<<<B, 64, 0, stream>>>(x, E, W_ih, W_hh, b_ih, b_hh,
                                           W_lin, b_lin, out, T);
}